// Round 11
// baseline (254.959 us; speedup 1.0000x reference)
//
#include <hip/hip_runtime.h>
#include <hip/hip_bf16.h>
#include <stdint.h>

// Problem constants
#define BB   32
#define CIN  128
#define HH   64
#define WW   64
#define COUT 256
#define OHH  62
#define OWW  62
#define PIX_PER_B (OHH*OWW)        // 3844
#define NPIX (BB*PIX_PER_B)        // 123008
#define KTOT (9*CIN)               // 1152
#define NKT2 18                    // K-tiles of BK=64
#define SLOT2 65536                // A 32KB + X 32KB per K-tile
#define NTBLK 481                  // ceil(NPIX/256)

typedef __bf16 bf16x8 __attribute__((ext_vector_type(8)));
typedef float  f32x4  __attribute__((ext_vector_type(4)));
typedef uint16_t u16x8 __attribute__((ext_vector_type(8)));

__device__ __forceinline__ uint16_t f2bf(float f) {
    uint32_t u = __float_as_uint(f);
    uint32_t r = (u + 0x7FFFu + ((u >> 16) & 1u)) >> 16;
    return (uint16_t)r;
}

__device__ __forceinline__ void gload_lds16(const void* g, void* l) {
    __builtin_amdgcn_global_load_lds(
        (const __attribute__((address_space(1))) uint32_t*)g,
        (__attribute__((address_space(3))) uint32_t*)l, 16, 0, 0);
}

// -------- Prepass 1: NCHW fp32 -> NHWC bf16 ----------------------------------
__global__ void __launch_bounds__(256) to_nhwc(const float* __restrict__ in,
                                               uint16_t* __restrict__ out) {
    int slab = blockIdx.x;            // b*64 + h
    int b = slab >> 6, h = slab & 63;
    int w  = threadIdx.x & 63;
    int cp = threadIdx.x >> 6;        // 0..3
    const float* src = in + (((size_t)b * CIN) * HH + h) * WW + w;
    uint16_t* dst = out + ((size_t)slab * WW + w) * CIN;
    #pragma unroll
    for (int it = 0; it < 4; ++it) {
        int c0 = cp * 32 + it * 8;
        u16x8 v;
        #pragma unroll
        for (int j = 0; j < 8; ++j) v[j] = f2bf(src[(c0 + j) * (HH * WW)]);
        *reinterpret_cast<u16x8*>(dst + c0) = v;
    }
}

// -------- Prepass 2: OIHW fp32 -> bf16 [o][uv*128 + c] -----------------------
__global__ void __launch_bounds__(256) pack_w(const float* __restrict__ w,
                                              uint16_t* __restrict__ out) {
    int idx = blockIdx.x * 256 + threadIdx.x;     // < 256*1152
    int o = idx / KTOT;
    int k = idx - o * KTOT;
    int uv = k >> 7, c = k & 127;
    out[idx] = f2bf(w[(o * CIN + c) * 9 + uv]);
}

// -------- Main: 256x256 tile, 8 waves (2Mx4N, 128x64 each), BK=64 ------------
// Lean deep phase: {stage(t+1) [8 gll] -> other slot; 24 ds_read_b128;
// 64 MFMA (2 ks halves, setprio-wrapped); vmcnt(0); ONE barrier} x 18.
// 64 MFMA per wave per barrier (1240 cy/SIMD) amortizes the fixed ~300cy
// per-phase latency+sync overhead to ~12% (was ~33% at BK=32). Ring-2 LDS
// 2x64KB -> 1 block/CU (co-resident twin blocks proved worthless: lockstep).
// vmcnt(0) is free here: stage issued at phase top has ~2500cy of cover.
// Swizzle: 128B rows, 8 chunks; stored chunk = logical ^ (row&7) on both
// staging source and frag reads -> 2-way (free) on reads, linear writes.
__global__ void __launch_bounds__(512, 2) conv_bk64(
        const uint16_t* __restrict__ Xg,   // NHWC bf16 [32][64][64][128]
        const uint16_t* __restrict__ Wg,   // bf16 [256][1152], k=(uv,c)
        const float*    __restrict__ bias, // [256]
        float*          __restrict__ out)  // NCHW fp32 [32][256][62][62]
{
    __shared__ char lds[2 * SLOT2 + 2048];
    int* pbase = (int*)(lds + 2 * SLOT2);   // [256] NHWC elem off of pixel
    int* obase = pbase + 256;               // [256] out base (o=0), -1=invalid

    const int tid  = threadIdx.x;
    const int lane = tid & 63;
    const int wid  = tid >> 6;              // 0..7

    // bijective XCD swizzle: nwg=481, q=60, r=1
    int bid = blockIdx.x;
    int xcd = bid & 7, lid = bid >> 3;
    int nt  = (xcd == 0) ? lid : 61 + (xcd - 1) * 60 + lid;

    if (tid < 256) {
        int n     = nt * 256 + tid;
        int valid = n < NPIX;
        int nn    = valid ? n : NPIX - 1;
        int b     = nn / PIX_PER_B;
        int rem   = nn - b * PIX_PER_B;
        int oh    = rem / OWW;
        int ow    = rem - oh * OWW;
        pbase[tid] = ((b * 64 + oh) * 64 + ow) * 128;
        obase[tid] = valid ? b * (COUT * PIX_PER_B) + rem : -1;
    }
    __syncthreads();

    // ---- staging geometry: 8 gll/thread/stage. Instr covers row = tid>>3
    // (64 rows x 128B = 8KB each); stored chunk = tid&7 holds logical chunk
    // (tid&7) ^ ((tid>>3)&7)  [stored = logical ^ (row&7), involution].
    const int cs   = (((tid & 7) ^ ((tid >> 3) & 7)) << 4);
    const int ldst = tid * 16;
    const char* ap0 = (const char*)Wg + (((tid >> 3) +   0) * (KTOT * 2)) + cs;
    const char* ap1 = (const char*)Wg + (((tid >> 3) +  64) * (KTOT * 2)) + cs;
    const char* ap2 = (const char*)Wg + (((tid >> 3) + 128) * (KTOT * 2)) + cs;
    const char* ap3 = (const char*)Wg + (((tid >> 3) + 192) * (KTOT * 2)) + cs;
    const char* xp0 = (const char*)Xg + pbase[(tid >> 3) +   0] * 2 + cs;
    const char* xp1 = (const char*)Xg + pbase[(tid >> 3) +  64] * 2 + cs;
    const char* xp2 = (const char*)Xg + pbase[(tid >> 3) + 128] * 2 + cs;
    const char* xp3 = (const char*)Xg + pbase[(tid >> 3) + 192] * 2 + cs;

    // per-tile k offsets: Wg linear (t*128 B); X: (u<<14)|(v<<8)|((t&1)<<7)
    auto stage = [&](int t, char* dst) {
        int uv = t >> 1;
        int u  = (uv * 11) >> 5;             // uv/3 for uv<9
        int v  = uv - u * 3;
        int xo = (u << 14) | (v << 8) | ((t & 1) << 7);
        gload_lds16(ap0 + t * 128, dst + ldst);
        gload_lds16(ap1 + t * 128, dst +  8192 + ldst);
        gload_lds16(ap2 + t * 128, dst + 16384 + ldst);
        gload_lds16(ap3 + t * 128, dst + 24576 + ldst);
        gload_lds16(xp0 + xo, dst + 32768 + ldst);
        gload_lds16(xp1 + xo, dst + 40960 + ldst);
        gload_lds16(xp2 + xo, dst + 49152 + ldst);
        gload_lds16(xp3 + xo, dst + 57344 + ldst);
    };

    // ---- fragment ds_read byte offsets (slot-relative) ----
    const int wm = wid >> 2, wn = wid & 3;   // 2 M-waves x 4 N-waves
    int aro[8][2], xro[4][2];
    #pragma unroll
    for (int mi = 0; mi < 8; ++mi) {
        int row = wm * 128 + mi * 16 + (lane & 15);
        #pragma unroll
        for (int ks = 0; ks < 2; ++ks)
            aro[mi][ks] = row * 128 +
                (((ks * 4 + (lane >> 4)) ^ (row & 7)) << 4);
    }
    #pragma unroll
    for (int nj = 0; nj < 4; ++nj) {
        int row = wn * 64 + nj * 16 + (lane & 15);
        #pragma unroll
        for (int ks = 0; ks < 2; ++ks)
            xro[nj][ks] = 32768 + row * 128 +
                (((ks * 4 + (lane >> 4)) ^ (row & 7)) << 4);
    }

    f32x4 acc[8][4] = {};

// Phase T reading slot SB; optionally stage T+1 into the other slot.
#define PH(T, SB, STG, VMC, BAR) do {                                          \
    if (STG) stage((T) + 1, lds + (1 - (SB)) * SLOT2);                         \
    const char* _s = lds + (SB) * SLOT2;                                       \
    {                                                                          \
        bf16x8 af[8], xf[4];                                                   \
        _Pragma("unroll") for (int nj = 0; nj < 4; ++nj)                       \
            xf[nj] = *reinterpret_cast<const bf16x8*>(_s + xro[nj][0]);        \
        _Pragma("unroll") for (int mi = 0; mi < 8; ++mi)                       \
            af[mi] = *reinterpret_cast<const bf16x8*>(_s + aro[mi][0]);        \
        __builtin_amdgcn_s_setprio(1);                                         \
        _Pragma("unroll") for (int mi = 0; mi < 8; ++mi)                       \
          _Pragma("unroll") for (int nj = 0; nj < 4; ++nj)                     \
            acc[mi][nj] = __builtin_amdgcn_mfma_f32_16x16x32_bf16(             \
                af[mi], xf[nj], acc[mi][nj], 0, 0, 0);                         \
        __builtin_amdgcn_s_setprio(0);                                         \
    }                                                                          \
    {                                                                          \
        bf16x8 af[8], xf[4];                                                   \
        _Pragma("unroll") for (int nj = 0; nj < 4; ++nj)                       \
            xf[nj] = *reinterpret_cast<const bf16x8*>(_s + xro[nj][1]);        \
        _Pragma("unroll") for (int mi = 0; mi < 8; ++mi)                       \
            af[mi] = *reinterpret_cast<const bf16x8*>(_s + aro[mi][1]);        \
        __builtin_amdgcn_s_setprio(1);                                         \
        _Pragma("unroll") for (int mi = 0; mi < 8; ++mi)                       \
          _Pragma("unroll") for (int nj = 0; nj < 4; ++nj)                     \
            acc[mi][nj] = __builtin_amdgcn_mfma_f32_16x16x32_bf16(             \
                af[mi], xf[nj], acc[mi][nj], 0, 0, 0);                         \
        __builtin_amdgcn_s_setprio(0);                                         \
    }                                                                          \
    if (VMC) asm volatile("s_waitcnt vmcnt(0)" ::: "memory");                  \
    if (BAR) __builtin_amdgcn_s_barrier();                                     \
} while (0)

    // ---- prologue: stage tiles 0 and 1 (both slots) ----
    stage(0, lds);
    stage(1, lds + SLOT2);
    asm volatile("s_waitcnt vmcnt(8)" ::: "memory");   // tile 0 resident
    __builtin_amdgcn_s_barrier();

    // ---- main: t=0 (no stage), t=1..16 (stage t+1), t=17 (tail) ----
    PH(0, 0, 0, 1, 1);                  // vmcnt(0) drains stage(1)
    for (int i = 0; i < 8; ++i) {
        PH(2 * i + 1, 1, 1, 1, 1);      // stages 2i+2 -> slot 0
        PH(2 * i + 2, 0, 1, 1, 1);      // stages 2i+3 -> slot 1
    }
    PH(17, 1, 0, 0, 0);
#undef PH

    // ---- epilogue: C/D col=lane&15 (pixel), row=(lane>>4)*4+reg (o) ----
    #pragma unroll
    for (int mi = 0; mi < 8; ++mi) {
        int o = wm * 128 + mi * 16 + ((lane >> 4) << 2);
        #pragma unroll
        for (int reg = 0; reg < 4; ++reg) {
            float bv = bias[o + reg];
            #pragma unroll
            for (int nj = 0; nj < 4; ++nj) {
                int pl = wn * 64 + nj * 16 + (lane & 15);
                int ob = obase[pl];
                if (ob >= 0)
                    out[ob + (o + reg) * PIX_PER_B] = acc[mi][nj][reg] + bv;
            }
        }
    }
}

// -------- Fallback (ws too small): naive direct conv -------------------------
__global__ void __launch_bounds__(256) conv_naive(const float* __restrict__ in,
                                                  const float* __restrict__ w,
                                                  const float* __restrict__ bias,
                                                  float* __restrict__ out) {
    long idx = (long)blockIdx.x * 256 + threadIdx.x;
    int t = (int)idx;
    int ow = t % OWW; t /= OWW;
    int oh = t % OHH; t /= OHH;
    int o  = t % COUT;
    int b  = t / COUT;
    float s = bias[o];
    for (int c = 0; c < CIN; ++c)
        for (int u = 0; u < 3; ++u)
            for (int v = 0; v < 3; ++v)
                s += in[((b * CIN + c) * HH + oh + u) * WW + ow + v] *
                     w[((o * CIN + c) * 3 + u) * 3 + v];
    out[idx] = s;
}

extern "C" void kernel_launch(void* const* d_in, const int* in_sizes, int n_in,
                              void* d_out, int out_size, void* d_ws, size_t ws_size,
                              hipStream_t stream) {
    const float* in   = (const float*)d_in[0];
    const float* wt   = (const float*)d_in[1];
    const float* bias = (const float*)d_in[2];
    float* out = (float*)d_out;

    const size_t xg_elems = (size_t)BB * HH * WW * CIN;       // 33.5M bf16
    const size_t wg_elems = (size_t)COUT * KTOT;              // 295K bf16
    const size_t need = (xg_elems + wg_elems) * sizeof(uint16_t);

    if (ws_size < need) {
        long total = (long)BB * COUT * OHH * OWW;
        conv_naive<<<(int)((total + 255) / 256), 256, 0, stream>>>(in, wt, bias, out);
        return;
    }

    uint16_t* Xg = (uint16_t*)d_ws;
    uint16_t* Wg = Xg + xg_elems;

    to_nhwc<<<BB * HH, 256, 0, stream>>>(in, Xg);
    pack_w<<<(COUT * KTOT) / 256, 256, 0, stream>>>(wt, Wg);
    conv_bk64<<<NTBLK, 512, 0, stream>>>(Xg, Wg, bias, out);
}